// Round 1
// baseline (482.843 us; speedup 1.0000x reference)
//
#include <hip/hip_runtime.h>
#include <math.h>

#define NN 512
#define XD 256
#define ED 128
#define JC 32
#define NCHUNK (NN/JC)
#define SE_STRIDE 136   // shorts; rows 16B-aligned for ds b128
#define SY_STRIDE 264   // shorts; rows 16B-aligned for ds b128

typedef __attribute__((ext_vector_type(8))) short s8v;
typedef __attribute__((ext_vector_type(4))) float f4v;

__device__ __forceinline__ short f2bf(float f) {
    union { float f; unsigned u; } v; v.f = f;
    unsigned r = (v.u + 0x7FFFu + ((v.u >> 16) & 1u)) >> 16;
    return (short)r;
}
__device__ __forceinline__ s8v load8_bf(const float* __restrict__ p) {
    const float4* p4 = (const float4*)p;
    float4 a = p4[0], b = p4[1];
    s8v r;
    r[0]=f2bf(a.x); r[1]=f2bf(a.y); r[2]=f2bf(a.z); r[3]=f2bf(a.w);
    r[4]=f2bf(b.x); r[5]=f2bf(b.y); r[6]=f2bf(b.z); r[7]=f2bf(b.w);
    return r;
}
// single-instruction packed f32->bf16 (RNE), D[15:0]=lo, D[31:16]=hi
__device__ __forceinline__ unsigned cvt_pk_bf16(float lo, float hi) {
    unsigned r;
    asm("v_cvt_pk_bf16_f32 %0, %1, %2" : "=v"(r) : "v"(lo), "v"(hi));
    return r;
}

// ---------------- kernel 0: weights -> bf16 in MFMA-fragment order ----------------
// GEMM1/2 B-frag layout (Wem/Wea, W[c][k], 256x128):
//   frag f = (cb*4 + ks)*64 + quad*16 + l16  -> 8 shorts from W[cb*16+l16][ks*32+quad*8 ..]
// GEMM3 B-frag layout (Weo, W[oo][k], 128x256):
//   frag f = (ob*8 + ks)*64 + quad*16 + l16  -> 8 shorts from W[ob*16+l16][ks*32+quad*8 ..]
__global__ void wconv_kernel(const float* __restrict__ Wem, const float* __restrict__ Wea,
                             const float* __restrict__ Weo,
                             short* __restrict__ Wem_bf, short* __restrict__ Wea_bf,
                             short* __restrict__ Weo_bf) {
    const int f = blockIdx.x * 256 + threadIdx.x;   // [0, 4096)
    const int lane = f & 63;
    const int quad = lane >> 4;
    const int l16  = lane & 15;
    if (blockIdx.y < 2) {
        const float* src = blockIdx.y == 0 ? Wem : Wea;
        short* dst = blockIdx.y == 0 ? Wem_bf : Wea_bf;
        const int cb = f >> 8;
        const int ks = (f >> 6) & 3;
        *(s8v*)(dst + (size_t)f * 8) =
            load8_bf(src + (size_t)(cb*16 + l16)*ED + ks*32 + quad*8);
    } else {
        const int ob = f >> 9;
        const int ks = (f >> 6) & 7;
        *(s8v*)(Weo_bf + (size_t)f * 8) =
            load8_bf(Weo + (size_t)(ob*16 + l16)*XD + ks*32 + quad*8);
    }
}

// ---------------- kernel 1: Q (pre-scaled), K, V ----------------
__global__ void qkv_kernel(const float* __restrict__ x,
                           const float* __restrict__ Wq, const float* __restrict__ bq,
                           const float* __restrict__ Wk, const float* __restrict__ bk,
                           const float* __restrict__ Wv, const float* __restrict__ bv,
                           float* __restrict__ out) {
    const int i = blockIdx.x, which = blockIdx.y, t = threadIdx.x;
    __shared__ float sx[XD];
    sx[t] = x[i*XD + t];
    __syncthreads();
    const float* W = which==0 ? Wq : (which==1 ? Wk : Wv);
    const float* b = which==0 ? bq : (which==1 ? bk : bv);
    const float4* W4 = (const float4*)(W + (size_t)t*XD);
    const float4* x4 = (const float4*)sx;
    float acc = 0.f;
    #pragma unroll 8
    for (int k4 = 0; k4 < XD/4; ++k4) {
        float4 w = W4[k4]; float4 xv = x4[k4];
        acc += w.x*xv.x + w.y*xv.y + w.z*xv.z + w.w*xv.w;
    }
    acc += b[t];
    if (which == 0) acc *= 0.17677669529663688f;  // 1/sqrt(32)
    out[((size_t)which*NN + i)*XD + t] = acc;
}

// ---------------- fused kernel: one block per i, loop over j-chunks ----------------
// Per chunk: stage e (double-buffered, prefetched) -> GEMM1/2 -> elementwise Y (kept
// in f32 regs) -> sY bf16 write -> in-register partial softmax (per-lane running
// m/l/a; MFMA C-layout puts each column's 32 rows on lanes {l16,l16+16,l16+32,l16+48})
// -> GEMM3 -> outE. Epilogue: shfl_xor butterfly finishes softmax, fused newX matvec.
__global__ __launch_bounds__(512, 4) void fused_kernel(
    const float* __restrict__ e,
    const float* __restrict__ Qs, const float* __restrict__ Km, const float* __restrict__ Vm,
    const short* __restrict__ Wem_bf, const float* __restrict__ bem,
    const short* __restrict__ Wea_bf, const float* __restrict__ bea,
    const short* __restrict__ Weo_bf, const float* __restrict__ beo,
    const float* __restrict__ Wxo, const float* __restrict__ bxo,
    float* __restrict__ outX, float* __restrict__ outE)
{
    __shared__ __align__(16) short sE[2][JC*SE_STRIDE];   // 2 x 8704 B
    __shared__ __align__(16) short sY[JC*SY_STRIDE];      // 16896 B (reused as sv[] in epilogue)

    const int i = blockIdx.x;
    const int t = threadIdx.x;
    const int wave = t >> 6;
    const int lane = t & 63;
    const int quad = (lane >> 4) & 3;
    const int l16  = lane & 15;
    const int wn0  = wave * 32;

    float q_l[2], bm1[2], bea_l[2];
    #pragma unroll
    for (int nt = 0; nt < 2; ++nt) {
        const int c = wn0 + nt*16 + l16;
        q_l[nt]   = Qs[i*XD + c];
        bm1[nt]   = bem[c] + 1.0f;
        bea_l[nt] = bea[c];
    }
    const int oo = wave*16 + l16;
    const float beo_l = beo[oo];

    // fragment-ordered weight pointers (coalesced: 16 B per lane)
    const s8v* W1p = (const s8v*)(Wem_bf + ((size_t)wave*8*64 + lane)*8);
    const s8v* W2p = (const s8v*)(Wea_bf + ((size_t)wave*8*64 + lane)*8);
    const s8v* W3p = (const s8v*)(Weo_bf + ((size_t)wave*8*64 + lane)*8);

    // e-staging addresses: thread t stages row sj, 8 floats at sk, per chunk
    const int sj = t >> 4;          // 0..31
    const int sk = (t & 15) * 8;    // 0..120
    const float4* esrc = (const float4*)(e + ((size_t)i*NN + sj)*ED + sk);
    // chunk stride in float4 units: JC*ED/4 = 1024

    // per-lane running softmax state over this lane's 8 rows (x2 columns)
    float rm[2] = {-INFINITY, -INFINITY};
    float rl[2] = {0.f, 0.f};
    float ra[2] = {0.f, 0.f};

    // prologue: load + stage chunk 0
    float4 pfa = esrc[0], pfb = esrc[1];
    {
        unsigned u0 = cvt_pk_bf16(pfa.x, pfa.y), u1 = cvt_pk_bf16(pfa.z, pfa.w);
        unsigned u2 = cvt_pk_bf16(pfb.x, pfb.y), u3 = cvt_pk_bf16(pfb.z, pfb.w);
        int4 pk; pk.x=(int)u0; pk.y=(int)u1; pk.z=(int)u2; pk.w=(int)u3;
        *(int4*)(&sE[0][sj*SE_STRIDE + sk]) = pk;
    }
    int cur = 0;

    #pragma unroll 1
    for (int ch = 0; ch < NCHUNK; ++ch) {
        const bool more = (ch + 1 < NCHUNK);
        if (more) {   // prefetch next chunk's e (consumed at loop bottom)
            const float4* p = esrc + (size_t)(ch+1)*1024;
            pfa = p[0]; pfb = p[1];
        }
        __syncthreads();   // sE[cur] published; sY free (prev GEMM3 done)

        // --- GEMM1/2: E1,E2 [32 x 256], B-frags streamed from L2 ---
        f4v acc1[2][2], acc2[2][2];
        #pragma unroll
        for (int mt = 0; mt < 2; ++mt)
            #pragma unroll
            for (int nt = 0; nt < 2; ++nt) {
                f4v z = {0.f, 0.f, 0.f, 0.f};
                acc1[mt][nt] = z; acc2[mt][nt] = z;
            }
        #pragma unroll
        for (int ks = 0; ks < 4; ++ks) {
            s8v a0 = *(const s8v*)(&sE[cur][(     l16)*SE_STRIDE + ks*32 + quad*8]);
            s8v a1 = *(const s8v*)(&sE[cur][(16 + l16)*SE_STRIDE + ks*32 + quad*8]);
            #pragma unroll
            for (int nt = 0; nt < 2; ++nt) {
                s8v b1 = W1p[(nt*4 + ks)*64];
                s8v b2 = W2p[(nt*4 + ks)*64];
                acc1[0][nt] = __builtin_amdgcn_mfma_f32_16x16x32_bf16(a0, b1, acc1[0][nt], 0, 0, 0);
                acc1[1][nt] = __builtin_amdgcn_mfma_f32_16x16x32_bf16(a1, b1, acc1[1][nt], 0, 0, 0);
                acc2[0][nt] = __builtin_amdgcn_mfma_f32_16x16x32_bf16(a0, b2, acc2[0][nt], 0, 0, 0);
                acc2[1][nt] = __builtin_amdgcn_mfma_f32_16x16x32_bf16(a1, b2, acc2[1][nt], 0, 0, 0);
            }
        }

        // --- elementwise: Y = qK*(E1+1) + E2, kept in f32 regs ---
        float y[2][2][4];
        const float* Kb = Km + ((size_t)ch*JC + quad*4)*XD + wn0 + l16;
        #pragma unroll
        for (int mt = 0; mt < 2; ++mt)
            #pragma unroll
            for (int nt = 0; nt < 2; ++nt)
                #pragma unroll
                for (int r = 0; r < 4; ++r) {
                    float e1 = acc1[mt][nt][r] + bm1[nt];
                    float e2 = acc2[mt][nt][r] + bea_l[nt];
                    float kv = Kb[(mt*16 + r)*XD + nt*16];
                    y[mt][nt][r] = q_l[nt]*kv*e1 + e2;
                }

        // --- sY bf16 write (for GEMM3) via packed converts ---
        #pragma unroll
        for (int mt = 0; mt < 2; ++mt)
            #pragma unroll
            for (int nt = 0; nt < 2; ++nt) {
                unsigned p01 = cvt_pk_bf16(y[mt][nt][0], y[mt][nt][1]);
                unsigned p23 = cvt_pk_bf16(y[mt][nt][2], y[mt][nt][3]);
                short* b = &sY[(mt*16 + quad*4)*SY_STRIDE + wn0 + nt*16 + l16];
                b[0]            = (short)p01;
                b[SY_STRIDE]    = (short)(p01 >> 16);
                b[2*SY_STRIDE]  = (short)p23;
                b[3*SY_STRIDE]  = (short)(p23 >> 16);
            }

        // --- in-register partial softmax (unrounded f32 y), merge into running ---
        {
            const float* Vb = Vm + ((size_t)ch*JC + quad*4)*XD + wn0 + l16;
            float vv[2][2][4];
            #pragma unroll
            for (int mt = 0; mt < 2; ++mt)
                #pragma unroll
                for (int nt = 0; nt < 2; ++nt)
                    #pragma unroll
                    for (int r = 0; r < 4; ++r)
                        vv[mt][nt][r] = Vb[(mt*16 + r)*XD + nt*16];
            #pragma unroll
            for (int nt = 0; nt < 2; ++nt) {
                float mc = fmaxf(
                    fmaxf(fmaxf(y[0][nt][0], y[0][nt][1]), fmaxf(y[0][nt][2], y[0][nt][3])),
                    fmaxf(fmaxf(y[1][nt][0], y[1][nt][1]), fmaxf(y[1][nt][2], y[1][nt][3])));
                float mn = fmaxf(rm[nt], mc);
                float s  = __expf(rm[nt] - mn);
                float l0 = rl[nt]*s, a0 = ra[nt]*s;   // rescale running
                float l1 = 0.f,      a1 = 0.f;
                #pragma unroll
                for (int r = 0; r < 4; ++r) {
                    float p0 = __expf(y[0][nt][r] - mn);
                    float p1 = __expf(y[1][nt][r] - mn);
                    l0 += p0; a0 += p0 * vv[0][nt][r];
                    l1 += p1; a1 += p1 * vv[1][nt][r];
                }
                rl[nt] = l0 + l1; ra[nt] = a0 + a1; rm[nt] = mn;
            }
        }

        __syncthreads();   // sY published

        // --- GEMM3: newE chunk [32 x 128] ---
        f4v acc3[2];
        {
            f4v z = {0.f, 0.f, 0.f, 0.f};
            acc3[0] = z; acc3[1] = z;
        }
        #pragma unroll
        for (int ks = 0; ks < 8; ++ks) {
            s8v b3 = W3p[ks*64];
            s8v a0 = *(const s8v*)(&sY[(     l16)*SY_STRIDE + ks*32 + quad*8]);
            s8v a1 = *(const s8v*)(&sY[(16 + l16)*SY_STRIDE + ks*32 + quad*8]);
            acc3[0] = __builtin_amdgcn_mfma_f32_16x16x32_bf16(a0, b3, acc3[0], 0, 0, 0);
            acc3[1] = __builtin_amdgcn_mfma_f32_16x16x32_bf16(a1, b3, acc3[1], 0, 0, 0);
        }
        #pragma unroll
        for (int mt = 0; mt < 2; ++mt)
            #pragma unroll
            for (int r = 0; r < 4; ++r) {
                const int jg = ch*JC + mt*16 + quad*4 + r;
                outE[((size_t)i*NN + jg)*ED + oo] = acc3[mt][r] + beo_l;
            }

        // --- stage prefetched chunk into the other buffer ---
        if (more) {
            unsigned u0 = cvt_pk_bf16(pfa.x, pfa.y), u1 = cvt_pk_bf16(pfa.z, pfa.w);
            unsigned u2 = cvt_pk_bf16(pfb.x, pfb.y), u3 = cvt_pk_bf16(pfb.z, pfb.w);
            int4 pk; pk.x=(int)u0; pk.y=(int)u1; pk.z=(int)u2; pk.w=(int)u3;
            *(int4*)(&sE[cur ^ 1][sj*SE_STRIDE + sk]) = pk;
            cur ^= 1;
        }
    }

    // --- epilogue: finish softmax across quads, then fused newX matvec ---
    __syncthreads();               // all waves done with sY (last GEMM3)
    float* sv = (float*)sY;        // reuse sY space for weighted_V [256]
    #pragma unroll
    for (int nt = 0; nt < 2; ++nt) {
        #pragma unroll
        for (int off = 16; off < 64; off <<= 1) {   // 16, 32: lanes sharing a column
            float mo = __shfl_xor(rm[nt], off);
            float lo = __shfl_xor(rl[nt], off);
            float ao = __shfl_xor(ra[nt], off);
            float mn = fmaxf(rm[nt], mo);
            float s  = __expf(rm[nt] - mn);
            float so = __expf(mo - mn);
            rl[nt] = rl[nt]*s + lo*so;
            ra[nt] = ra[nt]*s + ao*so;
            rm[nt] = mn;
        }
        if (quad == 0) sv[wn0 + nt*16 + l16] = ra[nt] / rl[nt];
    }
    __syncthreads();

    if (t < XD) {
        const float4* W4 = (const float4*)(Wxo + (size_t)t*XD);
        const float4* v4 = (const float4*)sv;
        float acc = 0.f;
        #pragma unroll 8
        for (int k4 = 0; k4 < XD/4; ++k4) {
            float4 w = W4[k4]; float4 v = v4[k4];
            acc += w.x*v.x + w.y*v.y + w.z*v.z + w.w*v.w;
        }
        outX[(size_t)i*XD + t] = acc + bxo[t];
    }
}

extern "C" void kernel_launch(void* const* d_in, const int* in_sizes, int n_in,
                              void* d_out, int out_size, void* d_ws, size_t ws_size,
                              hipStream_t stream) {
    const float* x   = (const float*)d_in[0];
    const float* e   = (const float*)d_in[1];
    // d_in[2] = adj (unused by reference)
    const float* Wq  = (const float*)d_in[3];
    const float* bq  = (const float*)d_in[4];
    const float* Wk  = (const float*)d_in[5];
    const float* bk  = (const float*)d_in[6];
    const float* Wv  = (const float*)d_in[7];
    const float* bv  = (const float*)d_in[8];
    const float* Wem = (const float*)d_in[9];
    const float* bem = (const float*)d_in[10];
    const float* Wea = (const float*)d_in[11];
    const float* bea = (const float*)d_in[12];
    const float* Wxo = (const float*)d_in[13];
    const float* bxo = (const float*)d_in[14];
    const float* Weo = (const float*)d_in[15];
    const float* beo = (const float*)d_in[16];

    float* ws = (float*)d_ws;
    float* Qs = ws;                              // [512][256] pre-scaled Q
    float* Km = ws + (size_t)NN*XD;              // [512][256]
    float* Vm = ws + (size_t)2*NN*XD;            // [512][256]
    short* Wem_bf = (short*)(ws + (size_t)3*NN*XD);   // fragment-ordered bf16
    short* Wea_bf = Wem_bf + (size_t)XD*ED;
    short* Weo_bf = Wea_bf + (size_t)XD*ED;

    float* outX = (float*)d_out;                 // [512][256]
    float* outE = outX + (size_t)NN*XD;          // [512][512][128]

    wconv_kernel<<<dim3(16, 3), 256, 0, stream>>>(Wem, Wea, Weo, Wem_bf, Wea_bf, Weo_bf);
    qkv_kernel<<<dim3(NN, 3), 256, 0, stream>>>(x, Wq, bq, Wk, bk, Wv, bv, ws);
    fused_kernel<<<NN, 512, 0, stream>>>(e, Qs, Km, Vm,
                                         Wem_bf, bem, Wea_bf, bea, Weo_bf, beo,
                                         Wxo, bxo, outX, outE);
}

// Round 2
// 384.817 us; speedup vs baseline: 1.2547x; 1.2547x over previous
//
#include <hip/hip_runtime.h>
#include <math.h>

#define NN 512
#define XD 256
#define ED 128
#define JC 32
#define NCHUNK (NN/JC)
#define SE_STRIDE 136   // shorts; rows 16B-aligned for ds b128
#define SY_STRIDE 264   // shorts; rows 16B-aligned for ds b128

typedef __attribute__((ext_vector_type(8))) short s8v;
typedef __attribute__((ext_vector_type(4))) float f4v;

__device__ __forceinline__ short f2bf(float f) {
    union { float f; unsigned u; } v; v.f = f;
    unsigned r = (v.u + 0x7FFFu + ((v.u >> 16) & 1u)) >> 16;
    return (short)r;
}
__device__ __forceinline__ s8v load8_bf(const float* __restrict__ p) {
    const float4* p4 = (const float4*)p;
    float4 a = p4[0], b = p4[1];
    s8v r;
    r[0]=f2bf(a.x); r[1]=f2bf(a.y); r[2]=f2bf(a.z); r[3]=f2bf(a.w);
    r[4]=f2bf(b.x); r[5]=f2bf(b.y); r[6]=f2bf(b.z); r[7]=f2bf(b.w);
    return r;
}
// single-instruction packed f32->bf16 (RNE), D[15:0]=lo, D[31:16]=hi
__device__ __forceinline__ unsigned cvt_pk_bf16(float lo, float hi) {
    unsigned r;
    asm("v_cvt_pk_bf16_f32 %0, %1, %2" : "=v"(r) : "v"(lo), "v"(hi));
    return r;
}

// ---------------- kernel 0: weights -> bf16 in MFMA-fragment order ----------------
// GEMM1/2 B-frag layout (Wem/Wea, W[c][k], 256x128):
//   frag f = (cb*4 + ks)*64 + quad*16 + l16  -> 8 shorts from W[cb*16+l16][ks*32+quad*8 ..]
// GEMM3 B-frag layout (Weo, W[oo][k], 128x256):
//   frag f = (ob*8 + ks)*64 + quad*16 + l16  -> 8 shorts from W[ob*16+l16][ks*32+quad*8 ..]
__global__ void wconv_kernel(const float* __restrict__ Wem, const float* __restrict__ Wea,
                             const float* __restrict__ Weo,
                             short* __restrict__ Wem_bf, short* __restrict__ Wea_bf,
                             short* __restrict__ Weo_bf) {
    const int f = blockIdx.x * 256 + threadIdx.x;   // [0, 4096)
    const int lane = f & 63;
    const int quad = lane >> 4;
    const int l16  = lane & 15;
    if (blockIdx.y < 2) {
        const float* src = blockIdx.y == 0 ? Wem : Wea;
        short* dst = blockIdx.y == 0 ? Wem_bf : Wea_bf;
        const int cb = f >> 8;
        const int ks = (f >> 6) & 3;
        *(s8v*)(dst + (size_t)f * 8) =
            load8_bf(src + (size_t)(cb*16 + l16)*ED + ks*32 + quad*8);
    } else {
        const int ob = f >> 9;
        const int ks = (f >> 6) & 7;
        *(s8v*)(Weo_bf + (size_t)f * 8) =
            load8_bf(Weo + (size_t)(ob*16 + l16)*XD + ks*32 + quad*8);
    }
}

// ---------------- kernel 1: Q (pre-scaled), K, V ----------------
__global__ void qkv_kernel(const float* __restrict__ x,
                           const float* __restrict__ Wq, const float* __restrict__ bq,
                           const float* __restrict__ Wk, const float* __restrict__ bk,
                           const float* __restrict__ Wv, const float* __restrict__ bv,
                           float* __restrict__ out) {
    const int i = blockIdx.x, which = blockIdx.y, t = threadIdx.x;
    __shared__ float sx[XD];
    sx[t] = x[i*XD + t];
    __syncthreads();
    const float* W = which==0 ? Wq : (which==1 ? Wk : Wv);
    const float* b = which==0 ? bq : (which==1 ? bk : bv);
    const float4* W4 = (const float4*)(W + (size_t)t*XD);
    const float4* x4 = (const float4*)sx;
    float acc = 0.f;
    #pragma unroll 8
    for (int k4 = 0; k4 < XD/4; ++k4) {
        float4 w = W4[k4]; float4 xv = x4[k4];
        acc += w.x*xv.x + w.y*xv.y + w.z*xv.z + w.w*xv.w;
    }
    acc += b[t];
    if (which == 0) acc *= 0.17677669529663688f;  // 1/sqrt(32)
    out[((size_t)which*NN + i)*XD + t] = acc;
}

// ---------------- kernel 2: pass 1 — one (i, j-chunk) per block ----------------
// Per block: stage e chunk -> GEMM1/2 -> elementwise Y kept in f32 regs -> sY bf16
// write (packed cvt) -> IN-REGISTER partial softmax (MFMA C-layout puts a column's
// 32 rows on lanes {l16, l16+16, l16+32, l16+48}; 2-step shfl_xor butterfly) ->
// GEMM3 -> outE + Pm/Pl/Pa. Two barriers total; no sY re-read; 16 exps/thread.
__global__ __launch_bounds__(512, 4) void pass1_kernel(
    const float* __restrict__ e,
    const float* __restrict__ Qs, const float* __restrict__ Km, const float* __restrict__ Vm,
    const short* __restrict__ Wem_bf, const float* __restrict__ bem,
    const short* __restrict__ Wea_bf, const float* __restrict__ bea,
    const short* __restrict__ Weo_bf, const float* __restrict__ beo,
    float* __restrict__ outE,
    float* __restrict__ Pm, float* __restrict__ Pl, float* __restrict__ Pa)
{
    __shared__ __align__(16) short sE[JC*SE_STRIDE];   // 8704 B
    __shared__ __align__(16) short sY[JC*SY_STRIDE];   // 16896 B

    const int ch = blockIdx.x;
    const int i  = blockIdx.y;
    const int t = threadIdx.x;
    const int wave = t >> 6;
    const int lane = t & 63;
    const int quad = (lane >> 4) & 3;
    const int l16 = lane & 15;
    const int wn0 = wave * 32;

    float q_l[2], bm1[2], bea_l[2];
    #pragma unroll
    for (int nt = 0; nt < 2; ++nt) {
        const int c = wn0 + nt*16 + l16;
        q_l[nt]   = Qs[i*XD + c];
        bm1[nt]   = bem[c] + 1.0f;
        bea_l[nt] = bea[c];
    }
    const int oo = wave*16 + l16;
    const float beo_l = beo[oo];

    // fragment-ordered weight pointers (coalesced: 16 B per lane)
    const s8v* W1p = (const s8v*)(Wem_bf + ((size_t)wave*8*64 + lane)*8);
    const s8v* W2p = (const s8v*)(Wea_bf + ((size_t)wave*8*64 + lane)*8);
    const s8v* W3p = (const s8v*)(Weo_bf + ((size_t)wave*8*64 + lane)*8);

    // --- stage e chunk -> LDS bf16 (packed converts) ---
    {
        const int sj = t >> 4;          // 0..31
        const int sk = (t & 15) * 8;    // 0..120
        const float4* p4 = (const float4*)(e + ((size_t)i*NN + (size_t)(ch*JC + sj))*ED + sk);
        float4 a = p4[0], b = p4[1];
        unsigned u0 = cvt_pk_bf16(a.x, a.y), u1 = cvt_pk_bf16(a.z, a.w);
        unsigned u2 = cvt_pk_bf16(b.x, b.y), u3 = cvt_pk_bf16(b.z, b.w);
        int4 pk; pk.x=(int)u0; pk.y=(int)u1; pk.z=(int)u2; pk.w=(int)u3;
        *(int4*)(&sE[sj*SE_STRIDE + sk]) = pk;
    }

    // issue K loads early so latency hides under the MFMA section
    const float* Kb = Km + ((size_t)(ch*JC) + quad*4)*XD + wn0 + l16;
    const float* Vb = Vm + ((size_t)(ch*JC) + quad*4)*XD + wn0 + l16;
    float kv[2][2][4];
    #pragma unroll
    for (int mt = 0; mt < 2; ++mt)
        #pragma unroll
        for (int nt = 0; nt < 2; ++nt)
            #pragma unroll
            for (int r = 0; r < 4; ++r)
                kv[mt][nt][r] = Kb[(mt*16 + r)*XD + nt*16];

    __syncthreads();

    // --- GEMM1/2: E1,E2 [32 x 256], B-frags streamed from L2 ---
    f4v acc1[2][2], acc2[2][2];
    #pragma unroll
    for (int mt = 0; mt < 2; ++mt)
        #pragma unroll
        for (int nt = 0; nt < 2; ++nt) {
            f4v z = {0.f, 0.f, 0.f, 0.f};
            acc1[mt][nt] = z; acc2[mt][nt] = z;
        }
    #pragma unroll
    for (int ks = 0; ks < 4; ++ks) {
        s8v a0 = *(const s8v*)(&sE[(     l16)*SE_STRIDE + ks*32 + quad*8]);
        s8v a1 = *(const s8v*)(&sE[(16 + l16)*SE_STRIDE + ks*32 + quad*8]);
        #pragma unroll
        for (int nt = 0; nt < 2; ++nt) {
            s8v b1 = W1p[(nt*4 + ks)*64];
            s8v b2 = W2p[(nt*4 + ks)*64];
            acc1[0][nt] = __builtin_amdgcn_mfma_f32_16x16x32_bf16(a0, b1, acc1[0][nt], 0, 0, 0);
            acc1[1][nt] = __builtin_amdgcn_mfma_f32_16x16x32_bf16(a1, b1, acc1[1][nt], 0, 0, 0);
            acc2[0][nt] = __builtin_amdgcn_mfma_f32_16x16x32_bf16(a0, b2, acc2[0][nt], 0, 0, 0);
            acc2[1][nt] = __builtin_amdgcn_mfma_f32_16x16x32_bf16(a1, b2, acc2[1][nt], 0, 0, 0);
        }
    }

    // --- elementwise: Y = qK*(E1+1) + E2, kept in f32 regs ---
    float y[2][2][4];
    #pragma unroll
    for (int mt = 0; mt < 2; ++mt)
        #pragma unroll
        for (int nt = 0; nt < 2; ++nt)
            #pragma unroll
            for (int r = 0; r < 4; ++r) {
                float e1 = acc1[mt][nt][r] + bm1[nt];
                float e2 = acc2[mt][nt][r] + bea_l[nt];
                y[mt][nt][r] = q_l[nt]*kv[mt][nt][r]*e1 + e2;
            }

    // --- sY bf16 write (for GEMM3) via packed converts ---
    #pragma unroll
    for (int mt = 0; mt < 2; ++mt)
        #pragma unroll
        for (int nt = 0; nt < 2; ++nt) {
            unsigned p01 = cvt_pk_bf16(y[mt][nt][0], y[mt][nt][1]);
            unsigned p23 = cvt_pk_bf16(y[mt][nt][2], y[mt][nt][3]);
            short* b = &sY[(mt*16 + quad*4)*SY_STRIDE + wn0 + nt*16 + l16];
            b[0]            = (short)p01;
            b[SY_STRIDE]    = (short)(p01 >> 16);
            b[2*SY_STRIDE]  = (short)p23;
            b[3*SY_STRIDE]  = (short)(p23 >> 16);
        }

    // --- in-register partial softmax over this chunk's 32 rows ---
    // lanes {l16, l16+16, l16+32, l16+48} hold the 4 row-quads of column wn0+nt*16+l16
    float Mc[2], Lc[2], Ac[2];
    {
        float vv[2][2][4];
        #pragma unroll
        for (int mt = 0; mt < 2; ++mt)
            #pragma unroll
            for (int nt = 0; nt < 2; ++nt)
                #pragma unroll
                for (int r = 0; r < 4; ++r)
                    vv[mt][nt][r] = Vb[(mt*16 + r)*XD + nt*16];
        #pragma unroll
        for (int nt = 0; nt < 2; ++nt) {
            float m = fmaxf(
                fmaxf(fmaxf(y[0][nt][0], y[0][nt][1]), fmaxf(y[0][nt][2], y[0][nt][3])),
                fmaxf(fmaxf(y[1][nt][0], y[1][nt][1]), fmaxf(y[1][nt][2], y[1][nt][3])));
            m = fmaxf(m, __shfl_xor(m, 16));
            m = fmaxf(m, __shfl_xor(m, 32));
            float l = 0.f, a = 0.f;
            #pragma unroll
            for (int mt = 0; mt < 2; ++mt)
                #pragma unroll
                for (int r = 0; r < 4; ++r) {
                    float p = __expf(y[mt][nt][r] - m);
                    l += p;
                    a += p * vv[mt][nt][r];
                }
            l += __shfl_xor(l, 16); l += __shfl_xor(l, 32);
            a += __shfl_xor(a, 16); a += __shfl_xor(a, 32);
            Mc[nt] = m; Lc[nt] = l; Ac[nt] = a;
        }
    }

    __syncthreads();   // sY published

    // --- GEMM3: newE chunk [32 x 128], B-frags streamed ---
    f4v acc3[2];
    {
        f4v z = {0.f, 0.f, 0.f, 0.f};
        acc3[0] = z; acc3[1] = z;
    }
    #pragma unroll
    for (int ks = 0; ks < 8; ++ks) {
        s8v b3 = W3p[ks*64];
        s8v a0 = *(const s8v*)(&sY[(     l16)*SY_STRIDE + ks*32 + quad*8]);
        s8v a1 = *(const s8v*)(&sY[(16 + l16)*SY_STRIDE + ks*32 + quad*8]);
        acc3[0] = __builtin_amdgcn_mfma_f32_16x16x32_bf16(a0, b3, acc3[0], 0, 0, 0);
        acc3[1] = __builtin_amdgcn_mfma_f32_16x16x32_bf16(a1, b3, acc3[1], 0, 0, 0);
    }
    #pragma unroll
    for (int mt = 0; mt < 2; ++mt)
        #pragma unroll
        for (int r = 0; r < 4; ++r) {
            const int jg = ch*JC + mt*16 + quad*4 + r;
            outE[((size_t)i*NN + jg)*ED + oo] = acc3[mt][r] + beo_l;
        }

    // --- write partials (one lane set per column) ---
    if (quad == 0) {
        #pragma unroll
        for (int nt = 0; nt < 2; ++nt) {
            const size_t pb = ((size_t)i*NCHUNK + ch)*256 + wn0 + nt*16 + l16;
            Pm[pb] = Mc[nt];
            Pl[pb] = Lc[nt];
            Pa[pb] = Ac[nt];
        }
    }
}

// ---------------- kernel 3: pass 2 — combine partials + newX ----------------
__global__ void pass2_kernel(const float* __restrict__ Pm, const float* __restrict__ Pl,
                             const float* __restrict__ Pa,
                             const float* __restrict__ Wxo, const float* __restrict__ bxo,
                             float* __restrict__ outX) {
    const int i = blockIdx.x, t = threadIdx.x;
    float mloc[NCHUNK];
    float M = -INFINITY;
    #pragma unroll
    for (int ch = 0; ch < NCHUNK; ++ch) {
        mloc[ch] = Pm[((size_t)i*NCHUNK + ch)*256 + t];
        M = fmaxf(M, mloc[ch]);
    }
    float L = 0.f, A = 0.f;
    #pragma unroll
    for (int ch = 0; ch < NCHUNK; ++ch) {
        const size_t pb = ((size_t)i*NCHUNK + ch)*256 + t;
        float s = __expf(mloc[ch] - M);
        L += Pl[pb]*s;
        A += Pa[pb]*s;
    }
    __shared__ float sv[XD];
    sv[t] = A / L;
    __syncthreads();
    const float4* W4 = (const float4*)(Wxo + (size_t)t*XD);
    const float4* v4 = (const float4*)sv;
    float acc = 0.f;
    #pragma unroll 8
    for (int k4 = 0; k4 < XD/4; ++k4) {
        float4 w = W4[k4]; float4 v = v4[k4];
        acc += w.x*v.x + w.y*v.y + w.z*v.z + w.w*v.w;
    }
    outX[(size_t)i*XD + t] = acc + bxo[t];
}

extern "C" void kernel_launch(void* const* d_in, const int* in_sizes, int n_in,
                              void* d_out, int out_size, void* d_ws, size_t ws_size,
                              hipStream_t stream) {
    const float* x   = (const float*)d_in[0];
    const float* e   = (const float*)d_in[1];
    // d_in[2] = adj (unused by reference)
    const float* Wq  = (const float*)d_in[3];
    const float* bq  = (const float*)d_in[4];
    const float* Wk  = (const float*)d_in[5];
    const float* bk  = (const float*)d_in[6];
    const float* Wv  = (const float*)d_in[7];
    const float* bv  = (const float*)d_in[8];
    const float* Wem = (const float*)d_in[9];
    const float* bem = (const float*)d_in[10];
    const float* Wea = (const float*)d_in[11];
    const float* bea = (const float*)d_in[12];
    const float* Wxo = (const float*)d_in[13];
    const float* bxo = (const float*)d_in[14];
    const float* Weo = (const float*)d_in[15];
    const float* beo = (const float*)d_in[16];

    float* ws = (float*)d_ws;
    float* Qs = ws;                              // [512][256] pre-scaled Q
    float* Km = ws + (size_t)NN*XD;              // [512][256]
    float* Vm = ws + (size_t)2*NN*XD;            // [512][256]
    float* Pm = ws + (size_t)3*NN*XD;            // [512][16][256]
    float* Pl = Pm + (size_t)NN*NCHUNK*XD;
    float* Pa = Pl + (size_t)NN*NCHUNK*XD;
    short* Wem_bf = (short*)(Pa + (size_t)NN*NCHUNK*XD);   // fragment-ordered bf16
    short* Wea_bf = Wem_bf + (size_t)XD*ED;
    short* Weo_bf = Wea_bf + (size_t)XD*ED;

    float* outX = (float*)d_out;                 // [512][256]
    float* outE = outX + (size_t)NN*XD;          // [512][512][128]

    wconv_kernel<<<dim3(16, 3), 256, 0, stream>>>(Wem, Wea, Weo, Wem_bf, Wea_bf, Weo_bf);
    qkv_kernel<<<dim3(NN, 3), 256, 0, stream>>>(x, Wq, bq, Wk, bk, Wv, bv, ws);
    pass1_kernel<<<dim3(NCHUNK, NN), 512, 0, stream>>>(e, Qs, Km, Vm,
                                                       Wem_bf, bem, Wea_bf, bea,
                                                       Weo_bf, beo, outE, Pm, Pl, Pa);
    pass2_kernel<<<NN, 256, 0, stream>>>(Pm, Pl, Pa, Wxo, bxo, outX);
}